// Round 15
// baseline (441.020 us; speedup 1.0000x reference)
//
#include <hip/hip_runtime.h>
#include <hip/hip_bf16.h>
#include <stdint.h>

#define D 1024
#define NSUP 256
#define ROWS 16384      // 4*4096
#define MB 32           // rows per block
#define LTHREADS 512    // 8 waves
#define LGRID (ROWS / MB)   // 512 blocks

typedef __attribute__((__ext_vector_type__(8))) __bf16 bf16x8;
typedef __attribute__((__ext_vector_type__(4))) float f32x4;

#define MFMA16(a, b, c) __builtin_amdgcn_mfma_f32_16x16x32_bf16((a), (b), (c), 0, 0, 0)

static __device__ __forceinline__ uint32_t bfbits(float f) {
    __bf16 b = (__bf16)f;
    return (uint32_t)*(uint16_t*)&b;
}

__global__ void cast_k_kernel(const float* __restrict__ K, __bf16* __restrict__ Kb) {
    int i = (blockIdx.x * 256 + threadIdx.x) * 4;
    float4 v = *(const float4*)(K + i);
    __bf16 o[4] __attribute__((aligned(8)));
    o[0] = (__bf16)v.x; o[1] = (__bf16)v.y; o[2] = (__bf16)v.z; o[3] = (__bf16)v.w;
    *(uint2*)(Kb + i) = *(const uint2*)o;
}

// V [4][256][1024] f32 -> Vt [4][1024][256] bf16
__global__ void transpose_v_kernel(const float* __restrict__ V, __bf16* __restrict__ Vt) {
    __shared__ __bf16 tile[64][72];
    int l = blockIdx.z;
    int d0 = blockIdx.x * 64, n0 = blockIdx.y * 64;
    const float* Vl = V + (size_t)l * NSUP * D;
    __bf16* Vtl = Vt + (size_t)l * D * NSUP;
    for (int j = 0; j < 16; ++j) {
        int idx = j * 256 + threadIdx.x;
        int n_l = idx >> 6, d_l = idx & 63;
        tile[d_l][n_l] = (__bf16)Vl[(size_t)(n0 + n_l) * D + d0 + d_l];
    }
    __syncthreads();
    for (int j = 0; j < 16; ++j) {
        int idx = j * 256 + threadIdx.x;
        int d_l = idx >> 6, n_l = idx & 63;
        Vtl[(size_t)(d0 + d_l) * NSUP + n0 + n_l] = tile[d_l][n_l];
    }
}

// One CleanUpKV layer, SWAPPED-OPERAND structure (r15):
//   Phase A computes scores^T = mfma(K-frag, h-frag): BOTH operands stream
//   from global/L2 straight into per-lane registers -> NO LDS staging of h,
//   no global_load_lds, no double-buffer, ZERO barriers inside Phase A.
//   acc[kg][hg][r] = score[n=wv*32+kg*16+lhi*4+r][hrow=hg*16+llo].
//   Softmax: reduction over n is (r,kg) in-lane + shfl over lhi + one small
//   LDS red across waves. w stored to a 16KB swizzled LDS tile [hrow][n].
//   Phase C computes out^T = mfma(V-frag, w-frag): V streams from L2,
//   w-frags from LDS (read once per ks; acc2[8][2] held across all dg).
//   Per-lane output runs are d-contiguous -> float4 / packed-uint2 stores.
// h between layers: LINEAR bf16 image (no swizzle needed - no LDS staging).
// rn via rnbuf (epilogue computes next layer's from f32 accumulators; folded
// into softmax exp). No softmax max-pass (|score*rn| <= |k| ~ 32 -> exp2
// arg <= ~46, f32-safe).
// 4 barriers per mid-layer. LDS ~18KB. 512 thr (REGISTER RULE: plain
// __launch_bounds__(512) only; 1024-thr or any occupancy attr pins VGPR=64
// and spills - rounds 3-12).
template<bool IN_F32, bool OUT_F32>
__global__ void __launch_bounds__(LTHREADS)
layer_kernel(const void* __restrict__ h_in, void* __restrict__ h_out,
             const __bf16* __restrict__ Kb, const __bf16* __restrict__ Vt,
             float* __restrict__ rnbuf) {
    __shared__ __align__(16) char wtile[16384];   // w[32][256] bf16, XOR-swizzled
    __shared__ float red[MB][8];
    __shared__ float rnin[MB];

    const int tid = threadIdx.x;
    const int lane = tid & 63;
    const int wv = tid >> 6;            // wave 0..7
    const int llo = lane & 15, lhi = lane >> 4;
    const int swzk = (llo & 7) << 4;    // swizzle key for w rows (llo, 16+llo)
    const int row0 = blockIdx.x * MB;

    // ---- rn source ----
    float rnv[2];
    if constexpr (IN_F32) {
        // compute 1/||x_row|| in-kernel (wave wv owns rows wv*4..+4)
        const float4* x4 = (const float4*)h_in;
        #pragma unroll
        for (int rr = 0; rr < 4; ++rr) {
            int row = wv * 4 + rr;
            const float4* p = x4 + (size_t)(row0 + row) * 256;
            float s = 0.f;
            #pragma unroll
            for (int j = 0; j < 4; ++j) {
                float4 v = p[j * 64 + lane];
                s += v.x * v.x + v.y * v.y + v.z * v.z + v.w * v.w;
            }
            #pragma unroll
            for (int off = 1; off < 64; off <<= 1) s += __shfl_xor(s, off);
            if (lane == 0) rnin[row] = 1.f / (sqrtf(s) + 1e-9f);
        }
        __syncthreads();
        rnv[0] = rnin[llo];
        rnv[1] = rnin[16 + llo];
    } else {
        rnv[0] = rnbuf[row0 + llo];        // issued early; latency hides under A
        rnv[1] = rnbuf[row0 + 16 + llo];
    }

    // ---------- Phase A: scores^T, barrier-free ----------
    f32x4 acc[2][2];   // [kg][hg]
    #pragma unroll
    for (int kg = 0; kg < 2; ++kg)
        #pragma unroll
        for (int hg = 0; hg < 2; ++hg)
            acc[kg][hg] = (f32x4){0.f, 0.f, 0.f, 0.f};

    const __bf16* kb0 = Kb + (size_t)(wv * 32 + llo) * D + lhi * 8;
    #pragma unroll
    for (int ks = 0; ks < 32; ++ks) {
        bf16x8 ka0 = *(const bf16x8*)(kb0 + ks * 32);
        bf16x8 ka1 = *(const bf16x8*)(kb0 + (size_t)16 * D + ks * 32);
        bf16x8 ha[2];
        #pragma unroll
        for (int hg = 0; hg < 2; ++hg) {
            if constexpr (IN_F32) {
                const float* xr = (const float*)h_in + (size_t)(row0 + hg * 16 + llo) * D
                                  + ks * 32 + lhi * 8;
                float4 f0 = *(const float4*)(xr);
                float4 f1 = *(const float4*)(xr + 4);
                __bf16 t[8] __attribute__((aligned(16)));
                t[0] = (__bf16)f0.x; t[1] = (__bf16)f0.y; t[2] = (__bf16)f0.z; t[3] = (__bf16)f0.w;
                t[4] = (__bf16)f1.x; t[5] = (__bf16)f1.y; t[6] = (__bf16)f1.z; t[7] = (__bf16)f1.w;
                ha[hg] = *(const bf16x8*)t;
            } else {
                ha[hg] = *(const bf16x8*)((const char*)h_in
                          + (size_t)(row0 + hg * 16 + llo) * 2048 + ks * 64 + lhi * 16);
            }
        }
        acc[0][0] = MFMA16(ka0, ha[0], acc[0][0]);
        acc[0][1] = MFMA16(ka0, ha[1], acc[0][1]);
        acc[1][0] = MFMA16(ka1, ha[0], acc[1][0]);
        acc[1][1] = MFMA16(ka1, ha[1], acc[1][1]);
    }

    // ---------- Softmax (rn folded, no max-pass) ----------
    float ee[2][2][4];
    float part[2] = {0.f, 0.f};
    #pragma unroll
    for (int kg = 0; kg < 2; ++kg)
        #pragma unroll
        for (int hg = 0; hg < 2; ++hg)
            #pragma unroll
            for (int r = 0; r < 4; ++r) {
                float e = exp2f(acc[kg][hg][r] * rnv[hg] * 1.44269504f);
                ee[kg][hg][r] = e;
                part[hg] += e;
            }
    #pragma unroll
    for (int hg = 0; hg < 2; ++hg) {
        part[hg] += __shfl_xor(part[hg], 16);
        part[hg] += __shfl_xor(part[hg], 32);
    }
    if (lhi == 0) {
        red[llo][wv] = part[0];
        red[16 + llo][wv] = part[1];
    }
    __syncthreads();   // bar1: exp partials visible
    #pragma unroll
    for (int hg = 0; hg < 2; ++hg) {
        int row = hg * 16 + llo;
        const f32x4* rp = (const f32x4*)&red[row][0];
        f32x4 s0 = rp[0], s1 = rp[1];
        float S = (s0[0] + s0[1] + s0[2] + s0[3]) + (s1[0] + s1[1] + s1[2] + s1[3]);
        float inv = 1.f / S;
        #pragma unroll
        for (int kg = 0; kg < 2; ++kg) {
            uint32_t p0 = bfbits(ee[kg][hg][0] * inv) | (bfbits(ee[kg][hg][1] * inv) << 16);
            uint32_t p1 = bfbits(ee[kg][hg][2] * inv) | (bfbits(ee[kg][hg][3] * inv) << 16);
            uint2 pk = {p0, p1};
            int nb = (wv * 32 + kg * 16 + lhi * 4) * 2;
            *(uint2*)(wtile + row * 512 + (nb ^ swzk)) = pk;
        }
    }
    __syncthreads();   // bar2: w visible

    // ---------- Phase C: out^T, barrier-free; acc2 spans all 8 d-groups ----------
    f32x4 acc2[8][2];  // [dg][hg]
    #pragma unroll
    for (int dg = 0; dg < 8; ++dg)
        #pragma unroll
        for (int hg = 0; hg < 2; ++hg)
            acc2[dg][hg] = (f32x4){0.f, 0.f, 0.f, 0.f};

    const __bf16* vt0 = Vt + (size_t)(wv * 128 + llo) * NSUP + lhi * 8;
    #pragma unroll
    for (int ks = 0; ks < 8; ++ks) {
        bf16x8 wa0 = *(const bf16x8*)(wtile + llo * 512 + ((ks * 64 + lhi * 16) ^ swzk));
        bf16x8 wa1 = *(const bf16x8*)(wtile + (16 + llo) * 512 + ((ks * 64 + lhi * 16) ^ swzk));
        #pragma unroll
        for (int dg = 0; dg < 8; ++dg) {
            bf16x8 va = *(const bf16x8*)(vt0 + (size_t)(dg * 16) * NSUP + ks * 32);
            acc2[dg][0] = MFMA16(va, wa0, acc2[dg][0]);
            acc2[dg][1] = MFMA16(va, wa1, acc2[dg][1]);
        }
    }

    // ---------- stores + next-layer rn ----------
    float sql[2] = {0.f, 0.f};
    #pragma unroll
    for (int dg = 0; dg < 8; ++dg)
        #pragma unroll
        for (int hg = 0; hg < 2; ++hg) {
            f32x4 v = acc2[dg][hg];
            sql[hg] += v[0] * v[0] + v[1] * v[1] + v[2] * v[2] + v[3] * v[3];
            int row = row0 + hg * 16 + llo;
            int dcol = wv * 128 + dg * 16 + lhi * 4;
            if constexpr (OUT_F32) {
                *(f32x4*)((float*)h_out + (size_t)row * D + dcol) = v;
            } else {
                uint2 pk = {bfbits(v[0]) | (bfbits(v[1]) << 16),
                            bfbits(v[2]) | (bfbits(v[3]) << 16)};
                *(uint2*)((char*)h_out + (size_t)row * 2048 + dcol * 2) = pk;
            }
        }

    if constexpr (!OUT_F32) {
        #pragma unroll
        for (int hg = 0; hg < 2; ++hg) {
            sql[hg] += __shfl_xor(sql[hg], 16);
            sql[hg] += __shfl_xor(sql[hg], 32);
        }
        __syncthreads();   // bar3: red free for reuse
        if (lhi == 0) {
            red[llo][wv] = sql[0];
            red[16 + llo][wv] = sql[1];
        }
        __syncthreads();   // bar4: sq partials visible
        if (tid < MB) {
            const f32x4* rp = (const f32x4*)&red[tid][0];
            f32x4 s0 = rp[0], s1 = rp[1];
            float S = (s0[0] + s0[1] + s0[2] + s0[3]) + (s1[0] + s1[1] + s1[2] + s1[3]);
            rnbuf[row0 + tid] = 1.f / (sqrtf(S) + 1e-9f);
        }
    }
}

extern "C" void kernel_launch(void* const* d_in, const int* in_sizes, int n_in,
                              void* d_out, int out_size, void* d_ws, size_t ws_size,
                              hipStream_t stream) {
    const float* x = (const float*)d_in[0];
    const float* keys = (const float*)d_in[1];
    const float* values = (const float*)d_in[2];
    float* out = (float*)d_out;

    char* ws = (char*)d_ws;
    char*   h  = ws;                            // 16384*2048 = 33554432 B (raw bf16, LINEAR)
    __bf16* Kb = (__bf16*)(ws + 33554432);      // 2 MB
    __bf16* Vt = (__bf16*)(ws + 35651584);      // 2 MB
    float*  rn = (float*)(ws + 37748736);       // 64 KB

    cast_k_kernel<<<1024, 256, 0, stream>>>(keys, Kb);
    transpose_v_kernel<<<dim3(16, 4, 4), 256, 0, stream>>>(values, Vt);

    const int LS = NSUP * D;
    layer_kernel<true,  false><<<LGRID, LTHREADS, 0, stream>>>(x, h, Kb,          Vt,          rn);
    layer_kernel<false, false><<<LGRID, LTHREADS, 0, stream>>>(h, h, Kb + LS,     Vt + LS,     rn);
    layer_kernel<false, false><<<LGRID, LTHREADS, 0, stream>>>(h, h, Kb + 2 * LS, Vt + 2 * LS, rn);
    layer_kernel<false, true ><<<LGRID, LTHREADS, 0, stream>>>(h, out, Kb + 3 * LS, Vt + 3 * LS, rn);
}